// Round 1
// baseline (1047.405 us; speedup 1.0000x reference)
//
#include <hip/hip_runtime.h>

#define THREADS 256

// ---------- preprocessing kernels ----------

// Detect whether edge_index is int64 (odd 32-bit words all zero) or int32.
__global__ void detect_kernel(const int* __restrict__ ei, int* __restrict__ flag) {
    if (blockIdx.x == 0 && threadIdx.x == 0) {
        int nz = 0;
        for (int i = 1; i < 256; i += 2) nz |= ei[i];
        *flag = (nz == 0) ? 1 : 0;  // 1 => int64 layout (index shift 1)
    }
}

__global__ void init_kernel(int* __restrict__ deg, int* __restrict__ counts, int n) {
    int i = blockIdx.x * blockDim.x + threadIdx.x;
    if (i < n) { deg[i] = 1; counts[i] = 1; }  // self-loop contributes 1 to both
}

__global__ void count_kernel(const int* __restrict__ ei, const int* __restrict__ flag,
                             int* __restrict__ deg, int* __restrict__ counts, int eN) {
    int e = blockIdx.x * blockDim.x + threadIdx.x;
    if (e >= eN) return;
    int sh = *flag;
    int r = ei[e << sh];          // source
    int c = ei[(eN + e) << sh];   // target
    atomicAdd(&deg[r], 1);
    atomicAdd(&counts[c], 1);
}

__global__ void dis_kernel(const int* __restrict__ deg, float* __restrict__ dis, int n) {
    int i = blockIdx.x * blockDim.x + threadIdx.x;
    if (i < n) dis[i] = 1.0f / sqrtf((float)deg[i]);
}

// Single-block exclusive scan of counts[n] -> offs[n+1].
__global__ void scan_kernel(const int* __restrict__ counts, int* __restrict__ offs, int n) {
    __shared__ int ls[1024];
    const int tid = threadIdx.x;
    const int chunk = (n + 1023) / 1024;
    const int s = tid * chunk;
    const int e2 = min(n, s + chunk);
    int sum = 0;
    for (int i = s; i < e2; ++i) sum += counts[i];
    ls[tid] = sum;
    __syncthreads();
    // Hillis-Steele inclusive scan over 1024 chunk sums
    for (int d = 1; d < 1024; d <<= 1) {
        int v = (tid >= d) ? ls[tid - d] : 0;
        __syncthreads();
        ls[tid] += v;
        __syncthreads();
    }
    int run = (tid > 0) ? ls[tid - 1] : 0;
    for (int i = s; i < e2; ++i) { offs[i] = run; run += counts[i]; }
    if (tid == 1023) offs[n] = ls[1023];
}

// Place self-loop at slot 0 of each node's segment; init fill cursor & sumw.
__global__ void selfloop_kernel(const float* __restrict__ dis, const int* __restrict__ offs,
                                uint2* __restrict__ csr, int* __restrict__ fill,
                                float* __restrict__ sumw, int n) {
    int i = blockIdx.x * blockDim.x + threadIdx.x;
    if (i >= n) return;
    float w = dis[i] * dis[i];
    int pos = offs[i];
    csr[pos] = make_uint2((unsigned)i, __float_as_uint(w));
    fill[i] = 1;
    sumw[i] = w;
}

__global__ void fill_kernel(const int* __restrict__ ei, const int* __restrict__ flag,
                            const float* __restrict__ dis, const int* __restrict__ offs,
                            int* __restrict__ fill, uint2* __restrict__ csr,
                            float* __restrict__ sumw, int eN) {
    int e = blockIdx.x * blockDim.x + threadIdx.x;
    if (e >= eN) return;
    int sh = *flag;
    int r = ei[e << sh];
    int c = ei[(eN + e) << sh];
    float w = dis[r] * dis[c];
    int pos = offs[c] + atomicAdd(&fill[c], 1);
    csr[pos] = make_uint2((unsigned)r, __float_as_uint(w));
    atomicAdd(&sumw[c], w);
}

// ---------- per-layer kernels ----------

// Weighted CSR aggregation: out[i] = sum_{e in in(i)} w_e * h[src_e]
// 32 lanes per node, each lane owns 4 consecutive floats (one float4).
__global__ void agg_kernel(const float4* __restrict__ h, const uint2* __restrict__ csr,
                           const int* __restrict__ offs, float4* __restrict__ out, int n) {
    int gid = blockIdx.x * (blockDim.x >> 5) + (threadIdx.x >> 5);
    int lane = threadIdx.x & 31;
    if (gid >= n) return;
    int s = offs[gid], e = offs[gid + 1];
    float4 acc = make_float4(0.f, 0.f, 0.f, 0.f);
    for (int j = s; j < e; ++j) {
        uint2 u = csr[j];
        float w = __uint_as_float(u.y);
        float4 v = h[(size_t)u.x * 32 + lane];
        acc.x += w * v.x; acc.y += w * v.y; acc.z += w * v.z; acc.w += w * v.w;
    }
    out[(size_t)gid * 32 + lane] = acc;
}

// Transpose W (128x128, row-major [out][in]) -> WT [in][out]
__global__ void transw_kernel(const float* __restrict__ w, float* __restrict__ wt) {
    int i = blockIdx.x * blockDim.x + threadIdx.x;
    if (i < 128 * 128) {
        int o = i >> 7, k = i & 127;
        wt[k * 128 + o] = w[i];
    }
}

// out[r][o] = relu( sum_k h[r][k] * WT[k][o] + sumw[r]*b[o] )
// Block: 32 rows x 128 cols. Thread: 4 rows x 4 cols register tile.
__global__ __launch_bounds__(THREADS) void lin_kernel(
    const float4* __restrict__ h, const float4* __restrict__ wt,
    const float* __restrict__ bias, const float* __restrict__ sumw,
    float4* __restrict__ out, int n) {
    __shared__ float4 sW[128 * 32];  // WT rows: [k][o/4] -> 64 KB
    __shared__ float4 sH[32 * 32];   // 32 feature rows -> 16 KB
    const int tid = threadIdx.x;
    const int row0 = blockIdx.x * 32;

    for (int i = tid; i < 128 * 32; i += THREADS) sW[i] = wt[i];
    for (int i = tid; i < 32 * 32; i += THREADS) {
        int r = row0 + (i >> 5);
        sH[i] = (r < n) ? h[(size_t)r * 32 + (i & 31)] : make_float4(0.f, 0.f, 0.f, 0.f);
    }
    __syncthreads();

    const int cg = tid & 31;   // col group: cols 4cg..4cg+3
    const int rg = tid >> 5;   // row group: rows rg*4..rg*4+3

    float4 acc[4];
#pragma unroll
    for (int j = 0; j < 4; ++j) acc[j] = make_float4(0.f, 0.f, 0.f, 0.f);

    for (int k4 = 0; k4 < 32; ++k4) {
        float4 w0 = sW[(4 * k4 + 0) * 32 + cg];
        float4 w1 = sW[(4 * k4 + 1) * 32 + cg];
        float4 w2 = sW[(4 * k4 + 2) * 32 + cg];
        float4 w3 = sW[(4 * k4 + 3) * 32 + cg];
#pragma unroll
        for (int j = 0; j < 4; ++j) {
            float4 hv = sH[(rg * 4 + j) * 32 + k4];
            acc[j].x += hv.x * w0.x + hv.y * w1.x + hv.z * w2.x + hv.w * w3.x;
            acc[j].y += hv.x * w0.y + hv.y * w1.y + hv.z * w2.y + hv.w * w3.y;
            acc[j].z += hv.x * w0.z + hv.y * w1.z + hv.z * w2.z + hv.w * w3.z;
            acc[j].w += hv.x * w0.w + hv.y * w1.w + hv.z * w2.w + hv.w * w3.w;
        }
    }

    const float4 b4 = reinterpret_cast<const float4*>(bias)[cg];
#pragma unroll
    for (int j = 0; j < 4; ++j) {
        int r = row0 + rg * 4 + j;
        if (r < n) {
            float sw = sumw[r];
            float4 o;
            o.x = fmaxf(acc[j].x + sw * b4.x, 0.f);
            o.y = fmaxf(acc[j].y + sw * b4.y, 0.f);
            o.z = fmaxf(acc[j].z + sw * b4.z, 0.f);
            o.w = fmaxf(acc[j].w + sw * b4.w, 0.f);
            out[(size_t)r * 32 + cg] = o;
        }
    }
}

// ---------- host launch ----------

extern "C" void kernel_launch(void* const* d_in, const int* in_sizes, int n_in,
                              void* d_out, int out_size, void* d_ws, size_t ws_size,
                              hipStream_t stream) {
    const float* x  = (const float*)d_in[0];
    const int*   ei = (const int*)d_in[1];
    const float* Ws[3] = {(const float*)d_in[2], (const float*)d_in[4], (const float*)d_in[6]};
    const float* bs[3] = {(const float*)d_in[3], (const float*)d_in[5], (const float*)d_in[7]};
    const int n = in_sizes[0] / 128;
    const int e = in_sizes[1] / 2;

    char* ws = (char*)d_ws;
    size_t cur = 0;
    auto alloc = [&](size_t bytes) {
        void* p = ws + cur;
        cur = (cur + bytes + 255) & ~(size_t)255;
        return p;
    };
    float* A      = (float*)alloc((size_t)n * 128 * 4);
    int*   deg    = (int*)  alloc((size_t)n * 4);
    float* dis    = (float*)alloc((size_t)n * 4);
    float* sumw   = (float*)alloc((size_t)n * 4);
    int*   counts = (int*)  alloc((size_t)n * 4);
    int*   offs   = (int*)  alloc(((size_t)n + 1) * 4);
    uint2* csr    = (uint2*)alloc((size_t)(e + n) * 8);
    float* wt     = (float*)alloc(128 * 128 * 4);
    int*   flag   = (int*)  alloc(4);

    float* B = (float*)d_out;

    detect_kernel<<<1, 64, 0, stream>>>(ei, flag);
    init_kernel<<<(n + 255) / 256, 256, 0, stream>>>(deg, counts, n);
    count_kernel<<<(e + 255) / 256, 256, 0, stream>>>(ei, flag, deg, counts, e);
    dis_kernel<<<(n + 255) / 256, 256, 0, stream>>>(deg, dis, n);
    scan_kernel<<<1, 1024, 0, stream>>>(counts, offs, n);
    selfloop_kernel<<<(n + 255) / 256, 256, 0, stream>>>(dis, offs, csr, counts, sumw, n);
    fill_kernel<<<(e + 255) / 256, 256, 0, stream>>>(ei, flag, dis, offs, counts, csr, sumw, e);

    const float* src = x;
    for (int l = 0; l < 3; ++l) {
        agg_kernel<<<(n + 7) / 8, 256, 0, stream>>>(
            (const float4*)src, csr, offs, (float4*)A, n);
        transw_kernel<<<(128 * 128 + 255) / 256, 256, 0, stream>>>(Ws[l], wt);
        lin_kernel<<<(n + 31) / 32, 256, 0, stream>>>(
            (const float4*)A, (const float4*)wt, bs[l], sumw, (float4*)B, n);
        src = B;
    }
}

// Round 2
// 862.505 us; speedup vs baseline: 1.2144x; 1.2144x over previous
//
#include <hip/hip_runtime.h>

#define THREADS 256

// ---------- preprocessing kernels ----------

// Detect whether edge_index is int64 (odd 32-bit words all zero) or int32.
__global__ void detect_kernel(const int* __restrict__ ei, int* __restrict__ flag) {
    if (blockIdx.x == 0 && threadIdx.x == 0) {
        int nz = 0;
        for (int i = 1; i < 256; i += 2) nz |= ei[i];
        *flag = (nz == 0) ? 1 : 0;  // 1 => int64 layout (index shift 1)
    }
}

__global__ void init_kernel(int* __restrict__ deg, int* __restrict__ counts, int n) {
    int i = blockIdx.x * blockDim.x + threadIdx.x;
    if (i < n) { deg[i] = 1; counts[i] = 1; }  // self-loop contributes 1 to both
}

__global__ void count_kernel(const int* __restrict__ ei, const int* __restrict__ flag,
                             int* __restrict__ deg, int* __restrict__ counts, int eN) {
    int e = blockIdx.x * blockDim.x + threadIdx.x;
    if (e >= eN) return;
    int sh = *flag;
    int r = ei[e << sh];          // source
    int c = ei[(eN + e) << sh];   // target
    atomicAdd(&deg[r], 1);
    atomicAdd(&counts[c], 1);
}

__global__ void dis_kernel(const int* __restrict__ deg, float* __restrict__ dis, int n) {
    int i = blockIdx.x * blockDim.x + threadIdx.x;
    if (i < n) dis[i] = 1.0f / sqrtf((float)deg[i]);
}

// ---------- hierarchical scan: counts[n] -> exclusive offs[n+1] ----------
// scanA: each block scans a 1024-element chunk (256 thr x 4), writes local
//        exclusive results to offs and the chunk total to bsum[block].
__global__ void scanA_kernel(const int* __restrict__ counts, int* __restrict__ offs,
                             int* __restrict__ bsum, int n) {
    __shared__ int ls[256];
    const int tid = threadIdx.x;
    const int idx0 = blockIdx.x * 1024 + tid * 4;
    int v[4];
    int s = 0;
#pragma unroll
    for (int j = 0; j < 4; ++j) {
        int i = idx0 + j;
        v[j] = (i < n) ? counts[i] : 0;
        s += v[j];
    }
    ls[tid] = s;
    __syncthreads();
    for (int d = 1; d < 256; d <<= 1) {
        int t = (tid >= d) ? ls[tid - d] : 0;
        __syncthreads();
        ls[tid] += t;
        __syncthreads();
    }
    int ex = (tid > 0) ? ls[tid - 1] : 0;
#pragma unroll
    for (int j = 0; j < 4; ++j) {
        int i = idx0 + j;
        if (i < n) offs[i] = ex;
        ex += v[j];
    }
    if (tid == 255) bsum[blockIdx.x] = ls[255];
}

// scanB: single small block, exclusive-scan bsum[nb] in place (nb <= 256*chunk).
__global__ void scanB_kernel(int* __restrict__ bsum, int nb) {
    __shared__ int ls[256];
    const int tid = threadIdx.x;
    const int chunk = (nb + 255) / 256;
    const int st = tid * chunk, en = min(nb, st + chunk);
    int s = 0;
    for (int i = st; i < en; ++i) s += bsum[i];
    ls[tid] = s;
    __syncthreads();
    for (int d = 1; d < 256; d <<= 1) {
        int t = (tid >= d) ? ls[tid - d] : 0;
        __syncthreads();
        ls[tid] += t;
        __syncthreads();
    }
    int run = (tid > 0) ? ls[tid - 1] : 0;
    for (int i = st; i < en; ++i) {
        int v = bsum[i];
        bsum[i] = run;
        run += v;
    }
}

// scanC: add block offsets; offs[n] = total (known analytically = e + n).
__global__ void scanC_kernel(int* __restrict__ offs, const int* __restrict__ bsum,
                             int n, int total) {
    int i = blockIdx.x * blockDim.x + threadIdx.x;
    if (i < n) offs[i] += bsum[i >> 10];
    else if (i == n) offs[n] = total;
}

// ---------- CSR fill ----------

// Place self-loop at slot 0 of each node's segment; init fill cursor & sumw.
__global__ void selfloop_kernel(const float* __restrict__ dis, const int* __restrict__ offs,
                                uint2* __restrict__ csr, int* __restrict__ fill,
                                float* __restrict__ sumw, int n) {
    int i = blockIdx.x * blockDim.x + threadIdx.x;
    if (i >= n) return;
    float w = dis[i] * dis[i];
    int pos = offs[i];
    csr[pos] = make_uint2((unsigned)i, __float_as_uint(w));
    fill[i] = 1;
    sumw[i] = w;
}

__global__ void fill_kernel(const int* __restrict__ ei, const int* __restrict__ flag,
                            const float* __restrict__ dis, const int* __restrict__ offs,
                            int* __restrict__ fill, uint2* __restrict__ csr,
                            float* __restrict__ sumw, int eN) {
    int e = blockIdx.x * blockDim.x + threadIdx.x;
    if (e >= eN) return;
    int sh = *flag;
    int r = ei[e << sh];
    int c = ei[(eN + e) << sh];
    float w = dis[r] * dis[c];
    int pos = offs[c] + atomicAdd(&fill[c], 1);
    csr[pos] = make_uint2((unsigned)r, __float_as_uint(w));
    atomicAdd(&sumw[c], w);
}

// ---------- per-layer kernels ----------

// Weighted CSR aggregation: out[i] = sum_{e in in(i)} w_e * h[src_e]
// 32 lanes per node, each lane owns one float4. 2x unrolled, dual accumulators.
__global__ void agg_kernel(const float4* __restrict__ h, const uint2* __restrict__ csr,
                           const int* __restrict__ offs, float4* __restrict__ out, int n) {
    int gid = blockIdx.x * (blockDim.x >> 5) + (threadIdx.x >> 5);
    int lane = threadIdx.x & 31;
    if (gid >= n) return;
    int s = offs[gid], e = offs[gid + 1];
    float4 a0 = make_float4(0.f, 0.f, 0.f, 0.f);
    float4 a1 = make_float4(0.f, 0.f, 0.f, 0.f);
    int j = s;
    for (; j + 2 <= e; j += 2) {
        uint2 u0 = csr[j], u1 = csr[j + 1];
        float w0 = __uint_as_float(u0.y), w1 = __uint_as_float(u1.y);
        float4 v0 = h[(size_t)u0.x * 32 + lane];
        float4 v1 = h[(size_t)u1.x * 32 + lane];
        a0.x += w0 * v0.x; a0.y += w0 * v0.y; a0.z += w0 * v0.z; a0.w += w0 * v0.w;
        a1.x += w1 * v1.x; a1.y += w1 * v1.y; a1.z += w1 * v1.z; a1.w += w1 * v1.w;
    }
    if (j < e) {
        uint2 u = csr[j];
        float w = __uint_as_float(u.y);
        float4 v = h[(size_t)u.x * 32 + lane];
        a0.x += w * v.x; a0.y += w * v.y; a0.z += w * v.z; a0.w += w * v.w;
    }
    a0.x += a1.x; a0.y += a1.y; a0.z += a1.z; a0.w += a1.w;
    out[(size_t)gid * 32 + lane] = a0;
}

// Transpose W (128x128, row-major [out][in]) -> WT [in][out]
__global__ void transw_kernel(const float* __restrict__ w, float* __restrict__ wt) {
    int i = blockIdx.x * blockDim.x + threadIdx.x;
    if (i < 128 * 128) {
        int o = i >> 7, k = i & 127;
        wt[k * 128 + o] = w[i];
    }
}

// out[r][o] = relu( sum_k h[r][k] * WT[k][o] + sumw[r]*b[o] )
// Grid-stride persistent blocks: sW loaded ONCE per block, then loop row tiles.
// Block: 32 rows x 128 cols per tile. Thread: 4 rows x 4 cols register tile.
__global__ __launch_bounds__(THREADS) void lin_kernel(
    const float4* __restrict__ h, const float4* __restrict__ wt,
    const float* __restrict__ bias, const float* __restrict__ sumw,
    float4* __restrict__ out, int n, int ntiles) {
    __shared__ float4 sW[128 * 32];  // WT rows: [k][o/4] -> 64 KB
    __shared__ float4 sH[32 * 32];   // 32 feature rows -> 16 KB
    const int tid = threadIdx.x;

    for (int i = tid; i < 128 * 32; i += THREADS) sW[i] = wt[i];

    const int cg = tid & 31;   // col group: cols 4cg..4cg+3
    const int rg = tid >> 5;   // row group: rows rg*4..rg*4+3
    const float4 b4 = reinterpret_cast<const float4*>(bias)[cg];

    for (int t = blockIdx.x; t < ntiles; t += gridDim.x) {
        const int row0 = t * 32;
        __syncthreads();  // previous tile's compute done before sH overwrite
        for (int i = tid; i < 32 * 32; i += THREADS) {
            int r = row0 + (i >> 5);
            sH[i] = (r < n) ? h[(size_t)r * 32 + (i & 31)]
                            : make_float4(0.f, 0.f, 0.f, 0.f);
        }
        __syncthreads();

        float4 acc[4];
#pragma unroll
        for (int j = 0; j < 4; ++j) acc[j] = make_float4(0.f, 0.f, 0.f, 0.f);

        for (int k4 = 0; k4 < 32; ++k4) {
            float4 w0 = sW[(4 * k4 + 0) * 32 + cg];
            float4 w1 = sW[(4 * k4 + 1) * 32 + cg];
            float4 w2 = sW[(4 * k4 + 2) * 32 + cg];
            float4 w3 = sW[(4 * k4 + 3) * 32 + cg];
#pragma unroll
            for (int j = 0; j < 4; ++j) {
                float4 hv = sH[(rg * 4 + j) * 32 + k4];
                acc[j].x += hv.x * w0.x + hv.y * w1.x + hv.z * w2.x + hv.w * w3.x;
                acc[j].y += hv.x * w0.y + hv.y * w1.y + hv.z * w2.y + hv.w * w3.y;
                acc[j].z += hv.x * w0.z + hv.y * w1.z + hv.z * w2.z + hv.w * w3.z;
                acc[j].w += hv.x * w0.w + hv.y * w1.w + hv.z * w2.w + hv.w * w3.w;
            }
        }

#pragma unroll
        for (int j = 0; j < 4; ++j) {
            int r = row0 + rg * 4 + j;
            if (r < n) {
                float sw = sumw[r];
                float4 o;
                o.x = fmaxf(acc[j].x + sw * b4.x, 0.f);
                o.y = fmaxf(acc[j].y + sw * b4.y, 0.f);
                o.z = fmaxf(acc[j].z + sw * b4.z, 0.f);
                o.w = fmaxf(acc[j].w + sw * b4.w, 0.f);
                out[(size_t)r * 32 + cg] = o;
            }
        }
    }
}

// ---------- host launch ----------

extern "C" void kernel_launch(void* const* d_in, const int* in_sizes, int n_in,
                              void* d_out, int out_size, void* d_ws, size_t ws_size,
                              hipStream_t stream) {
    const float* x  = (const float*)d_in[0];
    const int*   ei = (const int*)d_in[1];
    const float* Ws[3] = {(const float*)d_in[2], (const float*)d_in[4], (const float*)d_in[6]};
    const float* bs[3] = {(const float*)d_in[3], (const float*)d_in[5], (const float*)d_in[7]};
    const int n = in_sizes[0] / 128;
    const int e = in_sizes[1] / 2;

    char* ws = (char*)d_ws;
    size_t cur = 0;
    auto alloc = [&](size_t bytes) {
        void* p = ws + cur;
        cur = (cur + bytes + 255) & ~(size_t)255;
        return p;
    };
    float* A      = (float*)alloc((size_t)n * 128 * 4);
    int*   deg    = (int*)  alloc((size_t)n * 4);
    float* dis    = (float*)alloc((size_t)n * 4);
    float* sumw   = (float*)alloc((size_t)n * 4);
    int*   counts = (int*)  alloc((size_t)n * 4);
    int*   offs   = (int*)  alloc(((size_t)n + 1) * 4);
    uint2* csr    = (uint2*)alloc((size_t)(e + n) * 8);
    float* wt     = (float*)alloc(128 * 128 * 4);
    int*   flag   = (int*)  alloc(4);
    const int nScanBlocks = (n + 1023) / 1024;
    int*   bsum   = (int*)  alloc((size_t)nScanBlocks * 4);

    float* B = (float*)d_out;

    detect_kernel<<<1, 64, 0, stream>>>(ei, flag);
    init_kernel<<<(n + 255) / 256, 256, 0, stream>>>(deg, counts, n);
    count_kernel<<<(e + 255) / 256, 256, 0, stream>>>(ei, flag, deg, counts, e);
    dis_kernel<<<(n + 255) / 256, 256, 0, stream>>>(deg, dis, n);
    scanA_kernel<<<nScanBlocks, 256, 0, stream>>>(counts, offs, bsum, n);
    scanB_kernel<<<1, 256, 0, stream>>>(bsum, nScanBlocks);
    scanC_kernel<<<(n + 256) / 256, 256, 0, stream>>>(offs, bsum, n, e + n);
    selfloop_kernel<<<(n + 255) / 256, 256, 0, stream>>>(dis, offs, csr, counts, sumw, n);
    fill_kernel<<<(e + 255) / 256, 256, 0, stream>>>(ei, flag, dis, offs, counts, csr, sumw, e);

    const float* src = x;
    const int ntiles = (n + 31) / 32;
    for (int l = 0; l < 3; ++l) {
        agg_kernel<<<(n + 7) / 8, 256, 0, stream>>>(
            (const float4*)src, csr, offs, (float4*)A, n);
        transw_kernel<<<(128 * 128 + 255) / 256, 256, 0, stream>>>(Ws[l], wt);
        lin_kernel<<<512, THREADS, 0, stream>>>(
            (const float4*)A, (const float4*)wt, bs[l], sumw, (float4*)B, n, ntiles);
        src = B;
    }
}

// Round 3
// 830.516 us; speedup vs baseline: 1.2611x; 1.0385x over previous
//
#include <hip/hip_runtime.h>

#define THREADS 256

// ---------- preprocessing kernels ----------

// Detect whether edge_index is int64 (odd 32-bit words all zero) or int32.
__global__ void detect_kernel(const int* __restrict__ ei, int* __restrict__ flag) {
    if (blockIdx.x == 0 && threadIdx.x == 0) {
        int nz = 0;
        for (int i = 1; i < 256; i += 2) nz |= ei[i];
        *flag = (nz == 0) ? 1 : 0;  // 1 => int64 layout (index shift 1)
    }
}

__global__ void init_kernel(int* __restrict__ deg, int* __restrict__ counts, int n) {
    int i = blockIdx.x * blockDim.x + threadIdx.x;
    if (i < n) { deg[i] = 1; counts[i] = 1; }  // self-loop contributes 1 to both
}

__global__ void count_kernel(const int* __restrict__ ei, const int* __restrict__ flag,
                             int* __restrict__ deg, int* __restrict__ counts, int eN) {
    int e = blockIdx.x * blockDim.x + threadIdx.x;
    if (e >= eN) return;
    int sh = *flag;
    int r = ei[e << sh];          // source
    int c = ei[(eN + e) << sh];   // target
    atomicAdd(&deg[r], 1);
    atomicAdd(&counts[c], 1);
}

__global__ void dis_kernel(const int* __restrict__ deg, float* __restrict__ dis, int n) {
    int i = blockIdx.x * blockDim.x + threadIdx.x;
    if (i < n) dis[i] = 1.0f / sqrtf((float)deg[i]);
}

// ---------- hierarchical scan: counts[n] -> exclusive offs[n+1] ----------
__global__ void scanA_kernel(const int* __restrict__ counts, int* __restrict__ offs,
                             int* __restrict__ bsum, int n) {
    __shared__ int ls[256];
    const int tid = threadIdx.x;
    const int idx0 = blockIdx.x * 1024 + tid * 4;
    int v[4];
    int s = 0;
#pragma unroll
    for (int j = 0; j < 4; ++j) {
        int i = idx0 + j;
        v[j] = (i < n) ? counts[i] : 0;
        s += v[j];
    }
    ls[tid] = s;
    __syncthreads();
    for (int d = 1; d < 256; d <<= 1) {
        int t = (tid >= d) ? ls[tid - d] : 0;
        __syncthreads();
        ls[tid] += t;
        __syncthreads();
    }
    int ex = (tid > 0) ? ls[tid - 1] : 0;
#pragma unroll
    for (int j = 0; j < 4; ++j) {
        int i = idx0 + j;
        if (i < n) offs[i] = ex;
        ex += v[j];
    }
    if (tid == 255) bsum[blockIdx.x] = ls[255];
}

__global__ void scanB_kernel(int* __restrict__ bsum, int nb) {
    __shared__ int ls[256];
    const int tid = threadIdx.x;
    const int chunk = (nb + 255) / 256;
    const int st = tid * chunk, en = min(nb, st + chunk);
    int s = 0;
    for (int i = st; i < en; ++i) s += bsum[i];
    ls[tid] = s;
    __syncthreads();
    for (int d = 1; d < 256; d <<= 1) {
        int t = (tid >= d) ? ls[tid - d] : 0;
        __syncthreads();
        ls[tid] += t;
        __syncthreads();
    }
    int run = (tid > 0) ? ls[tid - 1] : 0;
    for (int i = st; i < en; ++i) {
        int v = bsum[i];
        bsum[i] = run;
        run += v;
    }
}

__global__ void scanC_kernel(int* __restrict__ offs, const int* __restrict__ bsum,
                             int n, int total) {
    int i = blockIdx.x * blockDim.x + threadIdx.x;
    if (i < n) offs[i] += bsum[i >> 10];
    else if (i == n) offs[n] = total;
}

// ---------- CSR fill (4-byte entries: src index only) ----------

__global__ void selfloop_kernel(const int* __restrict__ offs, int* __restrict__ csr,
                                int* __restrict__ fill, int n) {
    int i = blockIdx.x * blockDim.x + threadIdx.x;
    if (i >= n) return;
    csr[offs[i]] = i;   // self-loop at slot 0
    fill[i] = 1;
}

__global__ void fill_kernel(const int* __restrict__ ei, const int* __restrict__ flag,
                            const int* __restrict__ offs, int* __restrict__ fill,
                            int* __restrict__ csr, int eN) {
    int e = blockIdx.x * blockDim.x + threadIdx.x;
    if (e >= eN) return;
    int sh = *flag;
    int r = ei[e << sh];
    int c = ei[(eN + e) << sh];
    int pos = offs[c] + atomicAdd(&fill[c], 1);
    csr[pos] = r;
}

// sumw[i] = dis[i] * sum_{e in seg(i)} dis[src_e]   (bias aggregation factor)
__global__ void sumw_kernel(const int* __restrict__ csr, const int* __restrict__ offs,
                            const float* __restrict__ dis, float* __restrict__ sumw, int n) {
    int i = blockIdx.x * blockDim.x + threadIdx.x;
    if (i >= n) return;
    int s = offs[i], e = offs[i + 1];
    float t = 0.f;
    for (int j = s; j < e; ++j) t += dis[csr[j]];
    sumw[i] = dis[i] * t;
}

// ---------- per-layer kernels ----------

// Weighted CSR aggregation: out[i] = sum_{e in in(i)} dis[i]*dis[src]*h[src]
// 32 lanes per node, each lane owns one float4. 2x unrolled, dual accumulators.
__global__ void agg_kernel(const float4* __restrict__ h, const int* __restrict__ csr,
                           const int* __restrict__ offs, const float* __restrict__ dis,
                           float4* __restrict__ out, int n) {
    int gid = blockIdx.x * (blockDim.x >> 5) + (threadIdx.x >> 5);
    int lane = threadIdx.x & 31;
    if (gid >= n) return;
    int s = offs[gid], e = offs[gid + 1];
    float dg = dis[gid];
    float4 a0 = make_float4(0.f, 0.f, 0.f, 0.f);
    float4 a1 = make_float4(0.f, 0.f, 0.f, 0.f);
    int j = s;
    for (; j + 2 <= e; j += 2) {
        int u0 = csr[j], u1 = csr[j + 1];
        float w0 = dg * dis[u0], w1 = dg * dis[u1];
        float4 v0 = h[(size_t)u0 * 32 + lane];
        float4 v1 = h[(size_t)u1 * 32 + lane];
        a0.x += w0 * v0.x; a0.y += w0 * v0.y; a0.z += w0 * v0.z; a0.w += w0 * v0.w;
        a1.x += w1 * v1.x; a1.y += w1 * v1.y; a1.z += w1 * v1.z; a1.w += w1 * v1.w;
    }
    if (j < e) {
        int u = csr[j];
        float w = dg * dis[u];
        float4 v = h[(size_t)u * 32 + lane];
        a0.x += w * v.x; a0.y += w * v.y; a0.z += w * v.z; a0.w += w * v.w;
    }
    a0.x += a1.x; a0.y += a1.y; a0.z += a1.z; a0.w += a1.w;
    out[(size_t)gid * 32 + lane] = a0;
}

// Transpose all three W (128x128, row-major [out][in]) -> WT [layer][in][out]
__global__ void transw3_kernel(const float* __restrict__ w0, const float* __restrict__ w1,
                               const float* __restrict__ w2, float* __restrict__ wt) {
    int i = blockIdx.x * blockDim.x + threadIdx.x;
    if (i >= 3 * 128 * 128) return;
    int l = i >> 14, r = i & 16383;
    const float* w = (l == 0) ? w0 : (l == 1) ? w1 : w2;
    int o = r >> 7, k = r & 127;
    wt[l * 16384 + k * 128 + o] = w[r];
}

// out[r][o] = relu( sum_k h[r][k] * WT[k][o] + sumw[r]*b[o] )
// Grid-stride persistent blocks: sW loaded ONCE per block, then loop row tiles.
__global__ __launch_bounds__(THREADS) void lin_kernel(
    const float4* __restrict__ h, const float4* __restrict__ wt,
    const float* __restrict__ bias, const float* __restrict__ sumw,
    float4* __restrict__ out, int n, int ntiles) {
    __shared__ float4 sW[128 * 32];  // WT rows: [k][o/4] -> 64 KB
    __shared__ float4 sH[32 * 32];   // 32 feature rows -> 16 KB
    const int tid = threadIdx.x;

    for (int i = tid; i < 128 * 32; i += THREADS) sW[i] = wt[i];

    const int cg = tid & 31;   // col group: cols 4cg..4cg+3
    const int rg = tid >> 5;   // row group: rows rg*4..rg*4+3
    const float4 b4 = reinterpret_cast<const float4*>(bias)[cg];

    for (int t = blockIdx.x; t < ntiles; t += gridDim.x) {
        const int row0 = t * 32;
        __syncthreads();  // previous tile's compute done before sH overwrite
        for (int i = tid; i < 32 * 32; i += THREADS) {
            int r = row0 + (i >> 5);
            sH[i] = (r < n) ? h[(size_t)r * 32 + (i & 31)]
                            : make_float4(0.f, 0.f, 0.f, 0.f);
        }
        __syncthreads();

        float4 acc[4];
#pragma unroll
        for (int j = 0; j < 4; ++j) acc[j] = make_float4(0.f, 0.f, 0.f, 0.f);

        for (int k4 = 0; k4 < 32; ++k4) {
            float4 w0 = sW[(4 * k4 + 0) * 32 + cg];
            float4 w1 = sW[(4 * k4 + 1) * 32 + cg];
            float4 w2 = sW[(4 * k4 + 2) * 32 + cg];
            float4 w3 = sW[(4 * k4 + 3) * 32 + cg];
#pragma unroll
            for (int j = 0; j < 4; ++j) {
                float4 hv = sH[(rg * 4 + j) * 32 + k4];
                acc[j].x += hv.x * w0.x + hv.y * w1.x + hv.z * w2.x + hv.w * w3.x;
                acc[j].y += hv.x * w0.y + hv.y * w1.y + hv.z * w2.y + hv.w * w3.y;
                acc[j].z += hv.x * w0.z + hv.y * w1.z + hv.z * w2.z + hv.w * w3.z;
                acc[j].w += hv.x * w0.w + hv.y * w1.w + hv.z * w2.w + hv.w * w3.w;
            }
        }

#pragma unroll
        for (int j = 0; j < 4; ++j) {
            int r = row0 + rg * 4 + j;
            if (r < n) {
                float sw = sumw[r];
                float4 o;
                o.x = fmaxf(acc[j].x + sw * b4.x, 0.f);
                o.y = fmaxf(acc[j].y + sw * b4.y, 0.f);
                o.z = fmaxf(acc[j].z + sw * b4.z, 0.f);
                o.w = fmaxf(acc[j].w + sw * b4.w, 0.f);
                out[(size_t)r * 32 + cg] = o;
            }
        }
    }
}

// ---------- host launch ----------

extern "C" void kernel_launch(void* const* d_in, const int* in_sizes, int n_in,
                              void* d_out, int out_size, void* d_ws, size_t ws_size,
                              hipStream_t stream) {
    const float* x  = (const float*)d_in[0];
    const int*   ei = (const int*)d_in[1];
    const float* Ws[3] = {(const float*)d_in[2], (const float*)d_in[4], (const float*)d_in[6]};
    const float* bs[3] = {(const float*)d_in[3], (const float*)d_in[5], (const float*)d_in[7]};
    const int n = in_sizes[0] / 128;
    const int e = in_sizes[1] / 2;

    char* ws = (char*)d_ws;
    size_t cur = 0;
    auto alloc = [&](size_t bytes) {
        void* p = ws + cur;
        cur = (cur + bytes + 255) & ~(size_t)255;
        return p;
    };
    float* A      = (float*)alloc((size_t)n * 128 * 4);
    int*   deg    = (int*)  alloc((size_t)n * 4);
    float* dis    = (float*)alloc((size_t)n * 4);
    float* sumw   = (float*)alloc((size_t)n * 4);
    int*   counts = (int*)  alloc((size_t)n * 4);
    int*   offs   = (int*)  alloc(((size_t)n + 1) * 4);
    int*   csr    = (int*)  alloc((size_t)(e + n) * 4);
    float* wt     = (float*)alloc(3 * 128 * 128 * 4);
    int*   flag   = (int*)  alloc(4);
    const int nScanBlocks = (n + 1023) / 1024;
    int*   bsum   = (int*)  alloc((size_t)nScanBlocks * 4);

    float* B = (float*)d_out;

    detect_kernel<<<1, 64, 0, stream>>>(ei, flag);
    init_kernel<<<(n + 255) / 256, 256, 0, stream>>>(deg, counts, n);
    count_kernel<<<(e + 255) / 256, 256, 0, stream>>>(ei, flag, deg, counts, e);
    dis_kernel<<<(n + 255) / 256, 256, 0, stream>>>(deg, dis, n);
    scanA_kernel<<<nScanBlocks, 256, 0, stream>>>(counts, offs, bsum, n);
    scanB_kernel<<<1, 256, 0, stream>>>(bsum, nScanBlocks);
    scanC_kernel<<<(n + 256) / 256, 256, 0, stream>>>(offs, bsum, n, e + n);
    selfloop_kernel<<<(n + 255) / 256, 256, 0, stream>>>(offs, csr, counts, n);
    fill_kernel<<<(e + 255) / 256, 256, 0, stream>>>(ei, flag, offs, counts, csr, e);
    sumw_kernel<<<(n + 255) / 256, 256, 0, stream>>>(csr, offs, dis, sumw, n);
    transw3_kernel<<<(3 * 128 * 128 + 255) / 256, 256, 0, stream>>>(Ws[0], Ws[1], Ws[2], wt);

    const float* src = x;
    const int ntiles = (n + 31) / 32;
    for (int l = 0; l < 3; ++l) {
        agg_kernel<<<(n + 7) / 8, 256, 0, stream>>>(
            (const float4*)src, csr, offs, dis, (float4*)A, n);
        lin_kernel<<<512, THREADS, 0, stream>>>(
            (const float4*)A, (const float4*)(wt + l * 16384), bs[l], sumw, (float4*)B, n, ntiles);
        src = B;
    }
}